// Round 4
// baseline (184.783 us; speedup 1.0000x reference)
//
#include <hip/hip_runtime.h>
#include <math.h>

#define EMB_DIM 512
#define N_Q 8
#define GAMMA_F 12.0f
#define KB 8          // entity-iterations per wave between barriers

// ---------------------------------------------------------------------------
// Fused RotatE scoring, half-row-per-wave, K-batched barriers.
//
// Phase 1: block computes the 8 rotated queries into LDS (redundant across
//          blocks; __sincosf, ~1 us).
// Phase 2: wave w owns half h=w&1 of a row, entity slot e=w>>1. Lane l holds
//          q fragments for d in [h*256+4l, h*256+4l+4), all 8 queries: 64 VGPR.
// Phase 3: grid-stride, 2 entities per block-iteration. Inner batch of KB
//          iterations with rolling register prefetch and NO barrier (loads
//          stay in flight); per-iteration transposing butterfly leaves the 8
//          query sums on lanes 0..7, stored to a double-buffered LDS slab.
//          ONE __syncthreads per KB iterations (vmcnt-drain amortized 8x),
//          then 128 threads combine the two half-row partials and store.
// Occupancy: ~115 VGPR, 32+2 KB LDS -> 4 blocks/CU, 4 waves/SIMD.
// ---------------------------------------------------------------------------
__global__ __launch_bounds__(256, 4) void rotate_fused_kernel(
    const int* __restrict__ all_h,
    const int* __restrict__ all_r,
    const float* __restrict__ eemb,
    const float* __restrict__ remb,
    float* __restrict__ out,
    int N)
{
    __shared__ float lq[2 * N_Q * EMB_DIM];      // 32 KB: re_e[4096] | im_e[4096]
    __shared__ float part[2][4][KB][N_Q];        // 2 KB: [parity][wave][k][query]

    const int tid = threadIdx.x;

    // ---- Phase 1: rotated queries into LDS ----
    const float SCALE = (float)(M_PI * (double)EMB_DIM / 14.0);
    #pragma unroll
    for (int k = 0; k < 16; ++k) {
        int p = tid + 256 * k;              // p = b*512 + j
        int b = p >> 9;
        int j = p & (EMB_DIM - 1);
        int h = all_h[b];
        int r = all_r[b];
        float re_h = eemb[(size_t)h * (2 * EMB_DIM) + j];
        float im_h = eemb[(size_t)h * (2 * EMB_DIM) + EMB_DIM + j];
        float phase = remb[r * EMB_DIM + j] * SCALE;
        float s, c;
        __sincosf(phase, &s, &c);
        lq[p]                 = re_h * c - im_h * s;
        lq[N_Q * EMB_DIM + p] = re_h * s + im_h * c;
    }
    __syncthreads();

    const int lane = tid & 63;
    const int wid  = tid >> 6;
    const int half = wid & 1;     // which half-row this wave covers
    const int eoff = wid >> 1;    // which entity of the block's pair

    // ---- Phase 2: per-lane query fragments (8 queries x 4 complex) ----
    float4 qr[N_Q], qi[N_Q];
    #pragma unroll
    for (int b = 0; b < N_Q; ++b) {
        const float* qb = lq + b * EMB_DIM + half * 256 + 4 * lane;
        qr[b] = *(const float4*)(qb);
        qi[b] = *(const float4*)(qb + N_Q * EMB_DIM);
    }

    // ---- Phase 3: grid-stride, KB iterations per barrier ----
    const int base0  = blockIdx.x * 2;
    const int stride = gridDim.x * 2;
    const int iters  = (N - base0 + stride - 1) / stride;   // block-uniform
    const int nb     = (iters + KB - 1) / KB;

    const float* base_re = eemb + half * 256 + 4 * lane;

    float4 r0, i0, nr, ni;
    {
        const float* p = base_re + (size_t)(base0 + eoff) * (2 * EMB_DIM);
        r0 = *(const float4*)(p);
        i0 = *(const float4*)(p + EMB_DIM);
    }

    for (int g = 0; g < nb; ++g) {
        #pragma unroll
        for (int k = 0; k < KB; ++k) {
            const int itk = g * KB + k;
            if (itk < iters) {                      // block-uniform branch
                // prefetch next iteration's half-row (clamped)
                {
                    int n2 = base0 + eoff + (itk + 1) * stride;
                    int nc = (n2 < N) ? n2 : 0;
                    const float* p = base_re + (size_t)nc * (2 * EMB_DIM);
                    nr = *(const float4*)(p);
                    ni = *(const float4*)(p + EMB_DIM);
                }

                float acc[N_Q];
                #pragma unroll
                for (int b = 0; b < N_Q; ++b) {
                    float s = 0.f, dx, dy;
                    dx = qr[b].x - r0.x; dy = qi[b].x - i0.x; s += __builtin_amdgcn_sqrtf(fmaf(dx, dx, dy * dy));
                    dx = qr[b].y - r0.y; dy = qi[b].y - i0.y; s += __builtin_amdgcn_sqrtf(fmaf(dx, dx, dy * dy));
                    dx = qr[b].z - r0.z; dy = qi[b].z - i0.z; s += __builtin_amdgcn_sqrtf(fmaf(dx, dx, dy * dy));
                    dx = qr[b].w - r0.w; dy = qi[b].w - i0.w; s += __builtin_amdgcn_sqrtf(fmaf(dx, dx, dy * dy));
                    acc[b] = s;
                }

                // transposing butterfly: query (lane&7)'s 64-lane sum on all lanes
                const bool p1 = lane & 1;
                float u0, u1, u2, u3;
                {
                    float x, z;
                    x = p1 ? acc[1] : acc[0]; z = p1 ? acc[0] : acc[1]; u0 = x + __shfl_xor(z, 1);
                    x = p1 ? acc[3] : acc[2]; z = p1 ? acc[2] : acc[3]; u1 = x + __shfl_xor(z, 1);
                    x = p1 ? acc[5] : acc[4]; z = p1 ? acc[4] : acc[5]; u2 = x + __shfl_xor(z, 1);
                    x = p1 ? acc[7] : acc[6]; z = p1 ? acc[6] : acc[7]; u3 = x + __shfl_xor(z, 1);
                }
                const bool p2 = lane & 2;
                float t0, t1;
                {
                    float x, z;
                    x = p2 ? u1 : u0; z = p2 ? u0 : u1; t0 = x + __shfl_xor(z, 2);
                    x = p2 ? u3 : u2; z = p2 ? u2 : u3; t1 = x + __shfl_xor(z, 2);
                }
                const bool p3 = lane & 4;
                float u;
                {
                    float x, z;
                    x = p3 ? t1 : t0; z = p3 ? t0 : t1; u = x + __shfl_xor(z, 4);
                }
                u += __shfl_xor(u, 8);
                u += __shfl_xor(u, 16);
                u += __shfl_xor(u, 32);

                if (lane < N_Q) part[g & 1][wid][k][lane] = u;

                r0 = nr; i0 = ni;
            }
        }
        __syncthreads();

        // combine the two half-row partials; 128 threads cover e(2) x k(8) x b(8)
        if (tid < 2 * KB * N_Q) {
            int e = tid >> 6;               // KB*N_Q == 64
            int k = (tid >> 3) & (KB - 1);
            int b = tid & 7;
            int itk = g * KB + k;
            int n = base0 + e + itk * stride;
            if (itk < iters && n < N) {
                float v = part[g & 1][2 * e][k][b] + part[g & 1][2 * e + 1][k][b];
                out[(size_t)b * N + n] = GAMMA_F - v;
            }
        }
    }
}

extern "C" void kernel_launch(void* const* d_in, const int* in_sizes, int n_in,
                              void* d_out, int out_size, void* d_ws, size_t ws_size,
                              hipStream_t stream) {
    const int*   all_h = (const int*)d_in[0];
    const int*   all_r = (const int*)d_in[1];
    const float* eemb  = (const float*)d_in[2];
    const float* remb  = (const float*)d_in[3];
    float* out = (float*)d_out;

    int N = in_sizes[2] / (2 * EMB_DIM);   // 30000

    // 1024 blocks = 4 blocks/CU co-resident; 2 entities per block-iteration,
    // 8 iterations between barriers.
    rotate_fused_kernel<<<1024, 256, 0, stream>>>(all_h, all_r, eemb, remb, out, N);
}